// Round 6
// baseline (745.138 us; speedup 1.0000x reference)
//
#include <hip/hip_runtime.h>

typedef __bf16 bf16;
typedef __bf16 bf16x4 __attribute__((ext_vector_type(4)));
typedef __bf16 bf16x8 __attribute__((ext_vector_type(8)));
typedef float f32x4 __attribute__((ext_vector_type(4)));

#define BB 2
#define SS 2048
#define DIM 4096
#define KVDIM 1024
#define NH 32
#define NKV 8
#define HD 128
#define NEGINF (-1e30f)

__device__ __forceinline__ void async16(void* lds, const void* gmem) {
    __builtin_amdgcn_global_load_lds(
        (const __attribute__((address_space(1))) void*)gmem,
        (__attribute__((address_space(3))) void*)lds, 16, 0, 0);
}

__device__ __forceinline__ f32x4 mfma16(bf16x8 a, bf16x8 b, f32x4 c) {
    return __builtin_amdgcn_mfma_f32_16x16x32_bf16(a, b, c, 0, 0, 0);
}

// ---------------------------------------------------------------------------
// dtype detection (fp32 storage read as bf16 -> garbage magnitudes)
// ---------------------------------------------------------------------------
struct DetectArgs { const void* p[7]; int n[7]; };

__global__ void detect_dtypes(DetectArgs a, int* flags) {
    __shared__ int bad;
    const int ti = blockIdx.x;
    if (threadIdx.x == 0) bad = 0;
    __syncthreads();
    const bf16* s = (const bf16*)a.p[ti];
    int n = a.n[ti];
    int take = n < 8192 ? n : 8192;
    int lbad = 0;
    for (int i = threadIdx.x; i < take; i += 256) {
        float f = (float)s[i];
        if (!(f > -1e4f && f < 1e4f)) lbad = 1;
    }
    if (lbad) atomicOr(&bad, 1);
    __syncthreads();
    if (threadIdx.x == 0) flags[ti] = bad;
}

__device__ __forceinline__ void conv8(const void* src, bf16* dst, int rel, int flag) {
    if (flag) {
        const float* s = (const float*)src + (size_t)rel * 8;
        bf16x8 v;
#pragma unroll
        for (int j = 0; j < 8; ++j) v[j] = (bf16)s[j];
        *(bf16x8*)(dst + (size_t)rel * 8) = v;
    } else {
        *(bf16x8*)(dst + (size_t)rel * 8) = *((const bf16x8*)src + rel);
    }
}

__global__ void convert_to_bf16(const void* __restrict__ src, bf16* __restrict__ dst,
                                int n8, const int* __restrict__ flagp) {
    int i = blockIdx.x * 256 + threadIdx.x;
    if (i >= n8) return;
    conv8(src, dst, i, *flagp);
}

// fused multi-tensor convert (up to 4 segments; launch-count reduction)
__global__ void convert4(const void* s0, bf16* d0, int n0, const int* f0,
                         const void* s1, bf16* d1, int n1, const int* f1,
                         const void* s2, bf16* d2, int n2, const int* f2,
                         const void* s3, bf16* d3, int n3, const int* f3) {
    int u = blockIdx.x * 256 + threadIdx.x;
    if (u < n0)                       { conv8(s0, d0, u, *f0); return; }
    u -= n0;
    if (u < n1)                       { conv8(s1, d1, u, *f1); return; }
    u -= n1;
    if (u < n2)                       { conv8(s2, d2, u, *f2); return; }
    u -= n2;
    if (u < n3)                       { conv8(s3, d3, u, *f3); return; }
}

// ---------------------------------------------------------------------------
// 256x256 8-phase NT GEMM core (T2+T3+T4+T5 port, plain HIP).  (unchanged)
// ---------------------------------------------------------------------------
#define SBAR()  asm volatile("s_barrier" ::: "memory")
#define LGKM0() asm volatile("s_waitcnt lgkmcnt(0)" ::: "memory")
#define VM4()   asm volatile("s_waitcnt vmcnt(4)" ::: "memory")
#define VM2()   asm volatile("s_waitcnt vmcnt(2)" ::: "memory")
#define VM0()   asm volatile("s_waitcnt vmcnt(0)" ::: "memory")

__device__ __forceinline__ void gemm256_core(const bf16* __restrict__ A,
                                             const bf16* __restrict__ B,
                                             int K, int m0, int n0,
                                             f32x4 (&acc)[8][4]) {
    // [buf][region: A0,A1,B0,B1][128 rows * 64 k]
    __shared__ bf16 sm[2][4][8192];
    const int t = threadIdx.x;
    const int lane = t & 63;
    const int w = t >> 6;
    const int l15 = lane & 15, quad = lane >> 4;
    const int wm = w >> 2;           // 0..1
    const int wn = w & 3;            // 0..3
    const int axr = l15 & 7;
    const int c0 = (quad ^ axr) * 8;        // ks=0 swizzled chunk (elems)
    const int c1 = ((4 + quad) ^ axr) * 8;  // ks=1
    const int srl = t >> 3;                       // staging row (0..63)
    const int sch = ((t & 7) ^ (srl & 7)) * 8;    // staging src chunk (elems)
    const size_t Ks = (size_t)K;

    bf16x8 aReg[4][2], bReg[4][2];

#define RD_A(c_, mh) { \
    const bf16* ab = &sm[c_][wm][0] + ((mh) * 64 + l15) * 64; \
    _Pragma("unroll") for (int i = 0; i < 4; ++i) { \
        aReg[i][0] = *(const bf16x8*)(ab + i * 1024 + c0); \
        aReg[i][1] = *(const bf16x8*)(ab + i * 1024 + c1); } }

#define RD_B(c_, nh) { \
    const bf16* bb = &sm[c_][2 + (wn >> 1)][0] + ((wn & 1) * 64 + (nh) * 32 + l15) * 64; \
    _Pragma("unroll") for (int jj = 0; jj < 2; ++jj) { \
        bReg[(nh) * 2 + jj][0] = *(const bf16x8*)(bb + jj * 1024 + c0); \
        bReg[(nh) * 2 + jj][1] = *(const bf16x8*)(bb + jj * 1024 + c1); } }

#define STG(c_, reg_, Mat, rowbase, kt) { \
    bf16* d_ = &sm[c_][reg_][0] + (size_t)t * 8; \
    const bf16* s_ = (Mat) + ((size_t)((rowbase) + srl)) * Ks + (size_t)(kt) * 64 + sch; \
    async16(d_, s_); \
    async16(d_ + 4096, s_ + 64 * Ks); }

#define MM(mh, nh) { \
    _Pragma("unroll") for (int i = 0; i < 4; ++i) \
    _Pragma("unroll") for (int jj = 0; jj < 2; ++jj) { \
        acc[(mh) * 4 + i][(nh) * 2 + jj] = \
            mfma16(aReg[i][0], bReg[(nh) * 2 + jj][0], acc[(mh) * 4 + i][(nh) * 2 + jj]); \
        acc[(mh) * 4 + i][(nh) * 2 + jj] = \
            mfma16(aReg[i][1], bReg[(nh) * 2 + jj][1], acc[(mh) * 4 + i][(nh) * 2 + jj]); } }

    // prologue: K-tile 0 complete + B0(1), A0(1)   (12 loads; drain to 4)
    STG(0, 0, A, m0, 0);
    STG(0, 2, B, n0, 0);
    STG(0, 1, A, m0 + 128, 0);
    STG(0, 3, B, n0 + 128, 0);
    STG(1, 2, B, n0, 1);
    STG(1, 0, A, m0, 1);
    VM4(); SBAR();

    const int NT = K >> 6;
    for (int T = 0; T < NT; ++T) {
        const int c = T & 1, nc = c ^ 1;
        const int kt1 = (T + 1 < NT) ? T + 1 : 0;   // tail: dummy src, dead dst
        const int kt2 = (T + 2 < NT) ? T + 2 : 0;
        // ---- p0: A-m0 + B-n0 reads; stage A1(T+1)
        RD_A(c, 0); RD_B(c, 0);
        STG(nc, 1, A, m0 + 128, kt1);
        SBAR();
        __builtin_amdgcn_s_setprio(1); MM(0, 0); __builtin_amdgcn_s_setprio(0);
        LGKM0(); SBAR();
        // ---- p1: B-n1 reads; stage B1(T+1)
        RD_B(c, 1);
        STG(nc, 3, B, n0 + 128, kt1);
        SBAR();
        __builtin_amdgcn_s_setprio(1); MM(0, 1); __builtin_amdgcn_s_setprio(0);
        LGKM0(); SBAR();
        // ---- p2: A-m1 reads; stage B0(T+2) into just-dead region
        RD_A(c, 1);
        STG(c, 2, B, n0, kt2);
        SBAR();
        __builtin_amdgcn_s_setprio(1); MM(1, 0); __builtin_amdgcn_s_setprio(0);
        LGKM0(); SBAR();
        // ---- p3: stage A0(T+2); MFMA from regs; counted vmcnt (never 0)
        STG(c, 0, A, m0, kt2);
        SBAR();
        __builtin_amdgcn_s_setprio(1); MM(1, 1); __builtin_amdgcn_s_setprio(0);
        LGKM0(); VM4(); SBAR();
    }
#undef RD_A
#undef RD_B
#undef STG
#undef MM
}

__global__ __launch_bounds__(512, 2)
void gemm_nt(const bf16* __restrict__ A, const bf16* __restrict__ B,
             bf16* __restrict__ C, int M, int N, int K) {
    const int t = threadIdx.x, lane = t & 63, w = t >> 6;
    const int l15 = lane & 15, quad = lane >> 4;
    const int wm = w >> 2, wn = w & 3;
    const int m0 = blockIdx.y * 256, n0 = blockIdx.x * 256;
    f32x4 acc[8][4] = {};
    gemm256_core(A, B, K, m0, n0, acc);
#pragma unroll
    for (int i = 0; i < 8; ++i)
#pragma unroll
        for (int j = 0; j < 4; ++j) {
            int col = n0 + wn * 64 + j * 16 + l15;
#pragma unroll
            for (int r = 0; r < 4; ++r)
                C[(size_t)(m0 + wm * 128 + i * 16 + quad * 4 + r) * N + col] = (bf16)acc[i][j][r];
        }
}

// Fused K+V projection: B = concat(wk, wv); C split into Kc / Vc.
__global__ __launch_bounds__(512, 2)
void gemm_nt_kv(const bf16* __restrict__ A, const bf16* __restrict__ Bkv,
                bf16* __restrict__ Kc, bf16* __restrict__ Vc, int M, int K) {
    const int t = threadIdx.x, lane = t & 63, w = t >> 6;
    const int l15 = lane & 15, quad = lane >> 4;
    const int wm = w >> 2, wn = w & 3;
    const int m0 = blockIdx.y * 256, n0 = blockIdx.x * 256;
    f32x4 acc[8][4] = {};
    gemm256_core(A, Bkv, K, m0, n0, acc);
    bf16* C = (n0 < KVDIM) ? Kc : Vc;
    const int cb = (n0 < KVDIM) ? n0 : n0 - KVDIM;
#pragma unroll
    for (int i = 0; i < 8; ++i)
#pragma unroll
        for (int j = 0; j < 4; ++j) {
            int col = cb + wn * 64 + j * 16 + l15;
#pragma unroll
            for (int r = 0; r < 4; ++r)
                C[(size_t)(m0 + wm * 128 + i * 16 + quad * 4 + r) * KVDIM + col] = (bf16)acc[i][j][r];
        }
}

// O-proj with runtime output dtype
__global__ __launch_bounds__(512, 2)
void gemm_nt_out(const bf16* __restrict__ A, const bf16* __restrict__ B,
                 void* __restrict__ C, int M, int N, int K,
                 const int* __restrict__ flagp) {
    const int t = threadIdx.x, lane = t & 63, w = t >> 6;
    const int l15 = lane & 15, quad = lane >> 4;
    const int wm = w >> 2, wn = w & 3;
    const int m0 = blockIdx.y * 256, n0 = blockIdx.x * 256;
    const int f32out = *flagp;
    f32x4 acc[8][4] = {};
    gemm256_core(A, B, K, m0, n0, acc);
#pragma unroll
    for (int i = 0; i < 8; ++i)
#pragma unroll
        for (int j = 0; j < 4; ++j) {
            int col = n0 + wn * 64 + j * 16 + l15;
#pragma unroll
            for (int r = 0; r < 4; ++r) {
                int row = m0 + wm * 128 + i * 16 + quad * 4 + r;
                if (f32out) ((float*)C)[(size_t)row * N + col] = acc[i][j][r];
                else        ((bf16*)C)[(size_t)row * N + col] = (bf16)acc[i][j][r];
            }
        }
}

// ---------------------------------------------------------------------------
// Fused RoPE (Q pre-scaled by 1/sqrt(HD)*log2e) + V-transpose, one launch.
// ---------------------------------------------------------------------------
__device__ __forceinline__ void rope8(bf16* p, const bf16* fc, const bf16* fs,
                                      int s, int i0, float sc) {
    bf16x8 v = *(bf16x8*)p;
    bf16x8 o;
#pragma unroll
    for (int j = 0; j < 4; ++j) {
        float tr = (float)v[2 * j], ti = (float)v[2 * j + 1];
        float cc = (float)fc[s * 64 + i0 + j];
        float sn = (float)fs[s * 64 + i0 + j];
        o[2 * j]     = (bf16)((tr * cc - ti * sn) * sc);
        o[2 * j + 1] = (bf16)((tr * sn + ti * cc) * sc);
    }
    *(bf16x8*)p = o;
}

#define ROPE_BLOCKS ((DIM * (BB * SS) / 8 + KVDIM * (BB * SS) / 8) / 256)  // 10240

__global__ void rope_tv(bf16* __restrict__ Q, bf16* __restrict__ Kr,
                        const bf16* __restrict__ fc, const bf16* __restrict__ fs,
                        const bf16* __restrict__ V, bf16* __restrict__ Vt) {
    __shared__ bf16 tile[64][74];
    const int bid = blockIdx.x;
    const int t = threadIdx.x;
    if (bid < ROPE_BLOCKS) {
        const float qscale = 0.08838834764831845f * 1.4426950408889634f;
        int u = bid * 256 + t;
        const int QU = (DIM * (BB * SS)) / 8;
        if (u < QU) {
            int row = u >> 9;
            int c = (u & 511) * 8;
            rope8(Q + (size_t)row * DIM + c, fc, fs, row & (SS - 1), (c >> 1) & 63, qscale);
        } else {
            u -= QU;
            int row = u >> 7;
            int c = (u & 127) * 8;
            rope8(Kr + (size_t)row * KVDIM + c, fc, fs, row & (SS - 1), (c >> 1) & 63, 1.0f);
        }
        return;
    }
    // V transpose: Vt[((b*NKV+kvh)*HD + d)*S + s]
    const int b2 = bid - ROPE_BLOCKS;
    const int st = b2 & 31, ct = (b2 >> 5) & 15, b = b2 >> 9;
    const int s0 = st * 64;
    const int kvh = ct >> 1, d0 = (ct & 1) * 64;
#pragma unroll
    for (int i = 0; i < 2; ++i) {
        int o = i * 256 + t;
        int r = o >> 3, c8 = (o & 7) * 8;
        bf16x8 v = *(const bf16x8*)(V + (size_t)(b * SS + s0 + r) * KVDIM + kvh * HD + d0 + c8);
#pragma unroll
        for (int j = 0; j < 8; ++j) tile[r][c8 + j] = v[j];
    }
    __syncthreads();
#pragma unroll
    for (int i = 0; i < 2; ++i) {
        int o = i * 256 + t;
        int sseg = (o & 7) * 8, dl = o >> 3;
        bf16x8 v;
#pragma unroll
        for (int j = 0; j < 8; ++j) v[j] = tile[sseg + j][dl];
        *(bf16x8*)(Vt + ((size_t)((b * NKV + kvh) * HD) + d0 + dl) * SS + s0 + sseg) = v;
    }
}

// ---------------------------------------------------------------------------
// Flash attention, S^T formulation.
// R6: 8-wave / QBLK=256 blocks (was 4-wave / 128). Three scheduling tweaks
//   (counted vmcnt, defer-max, K-prefetch) all nulled at ~137us with
//   Occupancy ~20% (6.4 waves/CU vs static 12): the kernel is concurrency-
//   starved, not schedule-limited. Same 48KB LDS now serves 8 waves ->
//   16 waves/CU static (2 blocks x 8 waves; VGPR ~128 = 4 waves/SIMD),
//   2x latency hiding, and K/V staged once per 256 q-rows (block-tiles
//   halve: 17408 -> 9216). K-prefetch dropped (measured null; frees LDS
//   for P rows 128-255).
// LDS 48KB: Ks [64k x 128d] @0 (16K), P [256q x 64k] @0..32K (rows 0-127
//   alias Ks -- P is wave-private, only written after the post-QK barrier),
//   Vts [128d x 64k] @32K (16K).
// Per tile: stage K(2)+V(2); VM2 (K landed) SBAR; QK+mask+softmax
//   (defer-max THR=8); VM0 SBAR (V landed, Ks reads done); P-store
//   (own rows, lgkm only); PV; SBAR. Fully-masked tiles skip compute
//   (wave-uniform `live`), keep stages/waits/barriers.
// Epilogue: O staged via LDS in two 128-row halves (32KB each).
// ---------------------------------------------------------------------------
__global__ __launch_bounds__(512, 2)
void flash_attn(const bf16* __restrict__ Q, const bf16* __restrict__ Kr,
                const bf16* __restrict__ Vt, bf16* __restrict__ AO) {
    __shared__ char smem[49152];
    bf16* Ks  = (bf16*)smem;               // [64 keys][128 d], 16B-slot swizzled
    char* Ps  = smem;                       // P [256 q][64 k], rows 0-127 alias Ks
    bf16* Vts = (bf16*)(smem + 32768);     // [128 d][64 keys], swizzled
    const int t = threadIdx.x, w = t >> 6, lane = t & 63;
    const int l15 = lane & 15, quad = lane >> 4;
    const int bh = blockIdx.x;
    const int b = bh >> 5, h = bh & 31, kvh = h >> 2;
    const int q0 = ((int)gridDim.y - 1 - (int)blockIdx.y) * 256;  // LPT
    const int qw = q0 + w * 32;             // wave's first q row

#define STAGE_K(kk_) { \
    _Pragma("unroll") for (int i = 0; i < 2; ++i) { \
        int s_ = i * 512 + t; \
        int key_ = s_ >> 4, slot_ = s_ & 15; \
        int dseg_ = slot_ ^ (key_ & 15); \
        async16((char*)Ks + (size_t)s_ * 16, \
                Kr + (size_t)(b * SS + (kk_) + key_) * KVDIM + kvh * HD + dseg_ * 8); } }
#define STAGE_V(kk_) { \
    _Pragma("unroll") for (int i = 0; i < 2; ++i) { \
        int s_ = i * 512 + t; \
        int d_ = s_ >> 3, slot_ = s_ & 7; \
        int kseg_ = slot_ ^ (d_ & 7); \
        async16((char*)Vts + (size_t)s_ * 16, \
                Vt + ((size_t)((b * NKV + kvh) * HD + d_)) * SS + (kk_) + kseg_ * 8); } }

    bf16x8 qf[2][4];
#pragma unroll
    for (int mi = 0; mi < 2; ++mi) {
        int qrow = b * SS + qw + mi * 16 + l15;
#pragma unroll
        for (int ks = 0; ks < 4; ++ks)
            qf[mi][ks] = *(const bf16x8*)(Q + (size_t)qrow * DIM + h * HD + ks * 32 + quad * 8);
    }

    f32x4 of[2][8] = {};
    float mrow[2] = {NEGINF, NEGINF};
    float lrow[2] = {0.f, 0.f};

    const int kend = q0 + 256;
    for (int kk = 0; kk < kend; kk += 64) {
        STAGE_K(kk);
        STAGE_V(kk);
        VM2(); SBAR();                      // K landed (all waves); V in flight

        const bool live = kk <= qw + 31;    // any unmasked key for this wave?
        f32x4 sacc[2][4] = {};
        if (live) {
#pragma unroll
            for (int nt2 = 0; nt2 < 4; ++nt2) {
                int key = nt2 * 16 + l15;
#pragma unroll
                for (int ks = 0; ks < 4; ++ks) {
                    int slot = (ks * 4 + quad) ^ (key & 15);
                    bf16x8 kf = *(const bf16x8*)(Ks + key * 128 + slot * 8);
#pragma unroll
                    for (int mi = 0; mi < 2; ++mi)
                        sacc[mi][nt2] = mfma16(kf, qf[mi][ks], sacc[mi][nt2]);
                }
            }
            if (kk + 64 > qw) {             // boundary tile: apply causal mask
#pragma unroll
                for (int mi = 0; mi < 2; ++mi) {
                    int q = qw + mi * 16 + l15;
#pragma unroll
                    for (int nt2 = 0; nt2 < 4; ++nt2) {
                        int kbase = kk + nt2 * 16 + quad * 4;
#pragma unroll
                        for (int r = 0; r < 4; ++r)
                            if (kbase + r > q) sacc[mi][nt2][r] = NEGINF;
                    }
                }
            }
#pragma unroll
            for (int mi = 0; mi < 2; ++mi) {
                float m01[4];
#pragma unroll
                for (int nt2 = 0; nt2 < 4; ++nt2)
                    m01[nt2] = fmaxf(fmaxf(sacc[mi][nt2][0], sacc[mi][nt2][1]),
                                     fmaxf(sacc[mi][nt2][2], sacc[mi][nt2][3]));
                float mx = fmaxf(fmaxf(m01[0], m01[1]), fmaxf(m01[2], m01[3]));
                mx = fmaxf(mx, __shfl_xor(mx, 16));
                mx = fmaxf(mx, __shfl_xor(mx, 32));
                if (__all(mx - mrow[mi] <= 8.0f)) {
                    float rs[4];
#pragma unroll
                    for (int nt2 = 0; nt2 < 4; ++nt2) {
                        rs[nt2] = 0.f;
#pragma unroll
                        for (int r = 0; r < 4; ++r) {
                            float p = exp2f(sacc[mi][nt2][r] - mrow[mi]);
                            sacc[mi][nt2][r] = p;
                            rs[nt2] += p;
                        }
                    }
                    float rsum = (rs[0] + rs[1]) + (rs[2] + rs[3]);
                    rsum += __shfl_xor(rsum, 16);
                    rsum += __shfl_xor(rsum, 32);
                    lrow[mi] += rsum;
                } else {
                    float mnew = fmaxf(mrow[mi], mx);
                    float alpha = exp2f(mrow[mi] - mnew);
                    float rs[4];
#pragma unroll
                    for (int nt2 = 0; nt2 < 4; ++nt2) {
                        rs[nt2] = 0.f;
#pragma unroll
                        for (int r = 0; r < 4; ++r) {
                            float p = exp2f(sacc[mi][nt2][r] - mnew);
                            sacc[mi][nt2][r] = p;
                            rs[nt2] += p;
                        }
                    }
                    float rsum = (rs[0] + rs[1]) + (rs[2] + rs[3]);
                    rsum += __shfl_xor(rsum, 16);
                    rsum += __shfl_xor(rsum, 32);
                    lrow[mi] = lrow[mi] * alpha + rsum;
                    mrow[mi] = mnew;
#pragma unroll
                    for (int dt = 0; dt < 8; ++dt)
#pragma unroll
                        for (int r = 0; r < 4; ++r) of[mi][dt][r] *= alpha;
                }
            }
        }
        VM0(); SBAR();                      // V landed; all Ks reads done
        if (live) {
#pragma unroll
            for (int mi = 0; mi < 2; ++mi) {
                int row = w * 32 + mi * 16 + l15;
#pragma unroll
                for (int nt2 = 0; nt2 < 4; ++nt2) {
                    bf16x4 pv;
#pragma unroll
                    for (int r = 0; r < 4; ++r) pv[r] = (bf16)sacc[mi][nt2][r];
                    int cc = nt2 * 2 + (quad >> 1);
                    *(bf16x4*)(Ps + row * 128 + ((cc ^ (row & 7)) * 16 + (quad & 1) * 8)) = pv;
                }
            }
#pragma unroll
            for (int kb = 0; kb < 2; ++kb) {
                bf16x8 pa[2];
#pragma unroll
                for (int mi = 0; mi < 2; ++mi) {
                    int row = w * 32 + mi * 16 + l15;
                    pa[mi] = *(const bf16x8*)(Ps + row * 128 + (((kb * 4 + quad) ^ (row & 7)) * 16));
                }
#pragma unroll
                for (int dt = 0; dt < 8; ++dt) {
                    int d = dt * 16 + l15;
                    int slot = (kb * 4 + quad) ^ (d & 7);
                    bf16x8 vb = *(const bf16x8*)(Vts + d * 64 + slot * 8);
#pragma unroll
                    for (int mi = 0; mi < 2; ++mi)
                        of[mi][dt] = mfma16(vb, pa[mi], of[mi][dt]);
                }
            }
        }
        SBAR();                             // P/Vts reads done -> restage ok
    }
#undef STAGE_K
#undef STAGE_V
    // Epilogue: stage O through LDS in two 128-row halves (32KB each)
    bf16* Os = (bf16*)smem;
#pragma unroll
    for (int half = 0; half < 2; ++half) {
        __syncthreads();
        if ((w >> 2) == half) {
#pragma unroll
            for (int mi = 0; mi < 2; ++mi) {
                float inv = 1.0f / lrow[mi];
                int row = (w & 3) * 32 + mi * 16 + l15;
#pragma unroll
                for (int dt = 0; dt < 8; ++dt) {
                    bf16x4 o4;
#pragma unroll
                    for (int r = 0; r < 4; ++r) o4[r] = (bf16)(of[mi][dt][r] * inv);
                    int s = dt * 2 + (quad >> 1);
                    int slot = s ^ l15;
                    *(bf16x4*)((char*)Os + row * 256 + slot * 16 + (quad & 1) * 8) = o4;
                }
            }
        }
        __syncthreads();
#pragma unroll
        for (int i = 0; i < 4; ++i) {
            int flat = i * 512 + t;
            int ql = flat >> 4, s = flat & 15;
            bf16x8 v = *(const bf16x8*)((char*)Os + ql * 256 + (s ^ (ql & 15)) * 16);
            *(bf16x8*)(AO + (size_t)(b * SS + q0 + half * 128 + ql) * DIM + h * HD + s * 8) = v;
        }
    }
}

// ---------------------------------------------------------------------------
extern "C" void kernel_launch(void* const* d_in, const int* in_sizes, int n_in,
                              void* d_out, int out_size, void* d_ws, size_t ws_size,
                              hipStream_t stream) {
    const size_t MD = (size_t)BB * SS * DIM;    // 16,777,216
    const size_t KV = (size_t)BB * SS * KVDIM;  //  4,194,304
    const size_t FC = (size_t)SS * (HD / 2);
    const int M = BB * SS;

    int* flags = (int*)d_ws;
    bf16* xb  = (bf16*)((char*)d_ws + 32);  // x, later reused as attn output AO
    bf16* wb  = xb + MD;                    // weight staging (wq | wk+wv | wo)
    bf16* Q   = wb + MD;
    bf16* Kr  = Q + MD;
    bf16* Vw  = Kr + KV;
    bf16* Vt  = Vw + KV;
    bf16* fcb = Vt + KV;
    bf16* fsb = fcb + FC;

    DetectArgs da;
    for (int i = 0; i < 7; ++i) { da.p[i] = d_in[i]; da.n[i] = in_sizes[i]; }
    detect_dtypes<<<7, 256, 0, stream>>>(da, flags);

    dim3 blk(256);
    dim3 blk512(512);

    // fused convert #1: x, fc, fs, wq  (all needed before Q-proj)
    {
        int n0 = (int)(MD / 8), n1 = (int)(FC / 8), n2 = (int)(FC / 8), n3 = (int)(MD / 8);
        int nb = (n0 + n1 + n2 + n3 + 255) / 256;
        convert4<<<nb, blk, 0, stream>>>(d_in[0], xb, n0, flags + 0,
                                         d_in[5], fcb, n1, flags + 5,
                                         d_in[6], fsb, n2, flags + 6,
                                         d_in[1], wb, n3, flags + 1);
    }
    gemm_nt<<<dim3(DIM / 256, M / 256), blk512, 0, stream>>>(xb, wb, Q, M, DIM, DIM);

    // fused convert #2: wk, wv (into wb, contiguous)
    {
        int n0 = (int)(KV / 8), n1 = (int)(KV / 8);
        int nb = (n0 + n1 + 255) / 256;
        convert4<<<nb, blk, 0, stream>>>(d_in[2], wb, n0, flags + 2,
                                         d_in[3], wb + KV, n1, flags + 3,
                                         nullptr, nullptr, 0, flags + 2,
                                         nullptr, nullptr, 0, flags + 2);
    }
    gemm_nt_kv<<<dim3(2 * KVDIM / 256, M / 256), blk512, 0, stream>>>(xb, wb, Kr, Vw, M, DIM);

    // fused RoPE(Q,K) + V transpose
    rope_tv<<<dim3(ROPE_BLOCKS + (SS / 64) * 16 * BB), blk, 0, stream>>>(Q, Kr, fcb, fsb, Vw, Vt);

    // flash attention -> AO (reuses xb)
    flash_attn<<<dim3(BB * NH, SS / 256), blk512, 0, stream>>>(Q, Kr, Vt, xb);

    // output projection
    convert_to_bf16<<<(int)(MD / 8 / 256), blk, 0, stream>>>(d_in[4], wb, (int)(MD / 8), flags + 4);
    gemm_nt_out<<<dim3(DIM / 256, M / 256), blk512, 0, stream>>>(xb, wb, d_out, M, DIM, DIM, flags + 0);
}

// Round 7
// 711.391 us; speedup vs baseline: 1.0474x; 1.0474x over previous
//
#include <hip/hip_runtime.h>

typedef __bf16 bf16;
typedef __bf16 bf16x4 __attribute__((ext_vector_type(4)));
typedef __bf16 bf16x8 __attribute__((ext_vector_type(8)));
typedef float f32x4 __attribute__((ext_vector_type(4)));

#define BB 2
#define SS 2048
#define DIM 4096
#define KVDIM 1024
#define QKVN (DIM + 2 * KVDIM)   // 6144
#define NH 32
#define NKV 8
#define HD 128
#define NEGINF (-1e30f)

__device__ __forceinline__ void async16(void* lds, const void* gmem) {
    __builtin_amdgcn_global_load_lds(
        (const __attribute__((address_space(1))) void*)gmem,
        (__attribute__((address_space(3))) void*)lds, 16, 0, 0);
}

__device__ __forceinline__ f32x4 mfma16(bf16x8 a, bf16x8 b, f32x4 c) {
    return __builtin_amdgcn_mfma_f32_16x16x32_bf16(a, b, c, 0, 0, 0);
}

// ---------------------------------------------------------------------------
// dtype detection (fp32 storage read as bf16 -> garbage magnitudes)
// ---------------------------------------------------------------------------
struct DetectArgs { const void* p[7]; int n[7]; };

__global__ void detect_dtypes(DetectArgs a, int* flags) {
    __shared__ int bad;
    const int ti = blockIdx.x;
    if (threadIdx.x == 0) bad = 0;
    __syncthreads();
    const bf16* s = (const bf16*)a.p[ti];
    int n = a.n[ti];
    int take = n < 8192 ? n : 8192;
    int lbad = 0;
    for (int i = threadIdx.x; i < take; i += 256) {
        float f = (float)s[i];
        if (!(f > -1e4f && f < 1e4f)) lbad = 1;
    }
    if (lbad) atomicOr(&bad, 1);
    __syncthreads();
    if (threadIdx.x == 0) flags[ti] = bad;
}

__device__ __forceinline__ void conv8(const void* src, bf16* dst, int rel, int flag) {
    if (flag) {
        const float* s = (const float*)src + (size_t)rel * 8;
        bf16x8 v;
#pragma unroll
        for (int j = 0; j < 8; ++j) v[j] = (bf16)s[j];
        *(bf16x8*)(dst + (size_t)rel * 8) = v;
    } else {
        *(bf16x8*)(dst + (size_t)rel * 8) = *((const bf16x8*)src + rel);
    }
}

__global__ void convert_to_bf16(const void* __restrict__ src, bf16* __restrict__ dst,
                                int n8, const int* __restrict__ flagp) {
    int i = blockIdx.x * 256 + threadIdx.x;
    if (i >= n8) return;
    conv8(src, dst, i, *flagp);
}

// fused multi-tensor convert (6 segments; launch-count reduction)
struct Conv6 { const void* s[6]; bf16* d[6]; int n[6]; const int* f[6]; };

__global__ void convert6(Conv6 c) {
    int u = blockIdx.x * 256 + threadIdx.x;
#pragma unroll
    for (int i = 0; i < 6; ++i) {
        if (u < c.n[i]) { conv8(c.s[i], c.d[i], u, *c.f[i]); return; }
        u -= c.n[i];
    }
}

// ---------------------------------------------------------------------------
// 256x256 8-phase NT GEMM core (T2+T3+T4+T5 port, plain HIP).  (unchanged)
// ---------------------------------------------------------------------------
#define SBAR()  asm volatile("s_barrier" ::: "memory")
#define LGKM0() asm volatile("s_waitcnt lgkmcnt(0)" ::: "memory")
#define VM4()   asm volatile("s_waitcnt vmcnt(4)" ::: "memory")
#define VM0()   asm volatile("s_waitcnt vmcnt(0)" ::: "memory")

__device__ __forceinline__ void gemm256_core(const bf16* __restrict__ A,
                                             const bf16* __restrict__ B,
                                             int K, int m0, int n0,
                                             f32x4 (&acc)[8][4]) {
    // [buf][region: A0,A1,B0,B1][128 rows * 64 k]
    __shared__ bf16 sm[2][4][8192];
    const int t = threadIdx.x;
    const int lane = t & 63;
    const int w = t >> 6;
    const int l15 = lane & 15, quad = lane >> 4;
    const int wm = w >> 2;           // 0..1
    const int wn = w & 3;            // 0..3
    const int axr = l15 & 7;
    const int c0 = (quad ^ axr) * 8;        // ks=0 swizzled chunk (elems)
    const int c1 = ((4 + quad) ^ axr) * 8;  // ks=1
    const int srl = t >> 3;                       // staging row (0..63)
    const int sch = ((t & 7) ^ (srl & 7)) * 8;    // staging src chunk (elems)
    const size_t Ks = (size_t)K;

    bf16x8 aReg[4][2], bReg[4][2];

#define RD_A(c_, mh) { \
    const bf16* ab = &sm[c_][wm][0] + ((mh) * 64 + l15) * 64; \
    _Pragma("unroll") for (int i = 0; i < 4; ++i) { \
        aReg[i][0] = *(const bf16x8*)(ab + i * 1024 + c0); \
        aReg[i][1] = *(const bf16x8*)(ab + i * 1024 + c1); } }

#define RD_B(c_, nh) { \
    const bf16* bb = &sm[c_][2 + (wn >> 1)][0] + ((wn & 1) * 64 + (nh) * 32 + l15) * 64; \
    _Pragma("unroll") for (int jj = 0; jj < 2; ++jj) { \
        bReg[(nh) * 2 + jj][0] = *(const bf16x8*)(bb + jj * 1024 + c0); \
        bReg[(nh) * 2 + jj][1] = *(const bf16x8*)(bb + jj * 1024 + c1); } }

#define STG(c_, reg_, Mat, rowbase, kt) { \
    bf16* d_ = &sm[c_][reg_][0] + (size_t)t * 8; \
    const bf16* s_ = (Mat) + ((size_t)((rowbase) + srl)) * Ks + (size_t)(kt) * 64 + sch; \
    async16(d_, s_); \
    async16(d_ + 4096, s_ + 64 * Ks); }

#define MM(mh, nh) { \
    _Pragma("unroll") for (int i = 0; i < 4; ++i) \
    _Pragma("unroll") for (int jj = 0; jj < 2; ++jj) { \
        acc[(mh) * 4 + i][(nh) * 2 + jj] = \
            mfma16(aReg[i][0], bReg[(nh) * 2 + jj][0], acc[(mh) * 4 + i][(nh) * 2 + jj]); \
        acc[(mh) * 4 + i][(nh) * 2 + jj] = \
            mfma16(aReg[i][1], bReg[(nh) * 2 + jj][1], acc[(mh) * 4 + i][(nh) * 2 + jj]); } }

    // prologue: K-tile 0 complete + B0(1), A0(1)   (12 loads; drain to 4)
    STG(0, 0, A, m0, 0);
    STG(0, 2, B, n0, 0);
    STG(0, 1, A, m0 + 128, 0);
    STG(0, 3, B, n0 + 128, 0);
    STG(1, 2, B, n0, 1);
    STG(1, 0, A, m0, 1);
    VM4(); SBAR();

    const int NT = K >> 6;
    for (int T = 0; T < NT; ++T) {
        const int c = T & 1, nc = c ^ 1;
        const int kt1 = (T + 1 < NT) ? T + 1 : 0;   // tail: dummy src, dead dst
        const int kt2 = (T + 2 < NT) ? T + 2 : 0;
        // ---- p0: A-m0 + B-n0 reads; stage A1(T+1)
        RD_A(c, 0); RD_B(c, 0);
        STG(nc, 1, A, m0 + 128, kt1);
        SBAR();
        __builtin_amdgcn_s_setprio(1); MM(0, 0); __builtin_amdgcn_s_setprio(0);
        LGKM0(); SBAR();
        // ---- p1: B-n1 reads; stage B1(T+1)
        RD_B(c, 1);
        STG(nc, 3, B, n0 + 128, kt1);
        SBAR();
        __builtin_amdgcn_s_setprio(1); MM(0, 1); __builtin_amdgcn_s_setprio(0);
        LGKM0(); SBAR();
        // ---- p2: A-m1 reads; stage B0(T+2) into just-dead region
        RD_A(c, 1);
        STG(c, 2, B, n0, kt2);
        SBAR();
        __builtin_amdgcn_s_setprio(1); MM(1, 0); __builtin_amdgcn_s_setprio(0);
        LGKM0(); SBAR();
        // ---- p3: stage A0(T+2); MFMA from regs; counted vmcnt (never 0)
        STG(c, 0, A, m0, kt2);
        SBAR();
        __builtin_amdgcn_s_setprio(1); MM(1, 1); __builtin_amdgcn_s_setprio(0);
        LGKM0(); VM4(); SBAR();
    }
#undef RD_A
#undef RD_B
#undef STG
#undef MM
}

// Fused Q+K+V projection: B = concat(wq, wk, wv) rows (N = 6144).
// Output routed per 256-wide n0 tile (tiles never straddle 4096/5120).
__global__ __launch_bounds__(512, 2)
void gemm_qkv(const bf16* __restrict__ A, const bf16* __restrict__ Bqkv,
              bf16* __restrict__ Qo, bf16* __restrict__ Kc, bf16* __restrict__ Vc,
              int M, int K) {
    const int t = threadIdx.x, lane = t & 63, w = t >> 6;
    const int l15 = lane & 15, quad = lane >> 4;
    const int wm = w >> 2, wn = w & 3;
    const int m0 = blockIdx.y * 256, n0 = blockIdx.x * 256;
    f32x4 acc[8][4] = {};
    gemm256_core(A, Bqkv, K, m0, n0, acc);
    bf16* C;
    int cb;
    size_t ldc;
    if (n0 < DIM)               { C = Qo; cb = n0;                ldc = DIM; }
    else if (n0 < DIM + KVDIM)  { C = Kc; cb = n0 - DIM;          ldc = KVDIM; }
    else                        { C = Vc; cb = n0 - DIM - KVDIM;  ldc = KVDIM; }
#pragma unroll
    for (int i = 0; i < 8; ++i)
#pragma unroll
        for (int j = 0; j < 4; ++j) {
            int col = cb + wn * 64 + j * 16 + l15;
#pragma unroll
            for (int r = 0; r < 4; ++r)
                C[(size_t)(m0 + wm * 128 + i * 16 + quad * 4 + r) * ldc + col] = (bf16)acc[i][j][r];
        }
}

// O-proj with runtime output dtype
__global__ __launch_bounds__(512, 2)
void gemm_nt_out(const bf16* __restrict__ A, const bf16* __restrict__ B,
                 void* __restrict__ C, int M, int N, int K,
                 const int* __restrict__ flagp) {
    const int t = threadIdx.x, lane = t & 63, w = t >> 6;
    const int l15 = lane & 15, quad = lane >> 4;
    const int wm = w >> 2, wn = w & 3;
    const int m0 = blockIdx.y * 256, n0 = blockIdx.x * 256;
    const int f32out = *flagp;
    f32x4 acc[8][4] = {};
    gemm256_core(A, B, K, m0, n0, acc);
#pragma unroll
    for (int i = 0; i < 8; ++i)
#pragma unroll
        for (int j = 0; j < 4; ++j) {
            int col = n0 + wn * 64 + j * 16 + l15;
#pragma unroll
            for (int r = 0; r < 4; ++r) {
                int row = m0 + wm * 128 + i * 16 + quad * 4 + r;
                if (f32out) ((float*)C)[(size_t)row * N + col] = acc[i][j][r];
                else        ((bf16*)C)[(size_t)row * N + col] = (bf16)acc[i][j][r];
            }
        }
}

// ---------------------------------------------------------------------------
// Fused RoPE (Q pre-scaled by 1/sqrt(HD)*log2e) + V-transpose, one launch.
// ---------------------------------------------------------------------------
__device__ __forceinline__ void rope8(bf16* p, const bf16* fc, const bf16* fs,
                                      int s, int i0, float sc) {
    bf16x8 v = *(bf16x8*)p;
    bf16x8 o;
#pragma unroll
    for (int j = 0; j < 4; ++j) {
        float tr = (float)v[2 * j], ti = (float)v[2 * j + 1];
        float cc = (float)fc[s * 64 + i0 + j];
        float sn = (float)fs[s * 64 + i0 + j];
        o[2 * j]     = (bf16)((tr * cc - ti * sn) * sc);
        o[2 * j + 1] = (bf16)((tr * sn + ti * cc) * sc);
    }
    *(bf16x8*)p = o;
}

#define ROPE_BLOCKS ((DIM * (BB * SS) / 8 + KVDIM * (BB * SS) / 8) / 256)  // 10240

__global__ void rope_tv(bf16* __restrict__ Q, bf16* __restrict__ Kr,
                        const bf16* __restrict__ fc, const bf16* __restrict__ fs,
                        const bf16* __restrict__ V, bf16* __restrict__ Vt) {
    __shared__ bf16 tile[64][74];
    const int bid = blockIdx.x;
    const int t = threadIdx.x;
    if (bid < ROPE_BLOCKS) {
        const float qscale = 0.08838834764831845f * 1.4426950408889634f;
        int u = bid * 256 + t;
        const int QU = (DIM * (BB * SS)) / 8;
        if (u < QU) {
            int row = u >> 9;
            int c = (u & 511) * 8;
            rope8(Q + (size_t)row * DIM + c, fc, fs, row & (SS - 1), (c >> 1) & 63, qscale);
        } else {
            u -= QU;
            int row = u >> 7;
            int c = (u & 127) * 8;
            rope8(Kr + (size_t)row * KVDIM + c, fc, fs, row & (SS - 1), (c >> 1) & 63, 1.0f);
        }
        return;
    }
    // V transpose: Vt[((b*NKV+kvh)*HD + d)*S + s]
    const int b2 = bid - ROPE_BLOCKS;
    const int st = b2 & 31, ct = (b2 >> 5) & 15, b = b2 >> 9;
    const int s0 = st * 64;
    const int kvh = ct >> 1, d0 = (ct & 1) * 64;
#pragma unroll
    for (int i = 0; i < 2; ++i) {
        int o = i * 256 + t;
        int r = o >> 3, c8 = (o & 7) * 8;
        bf16x8 v = *(const bf16x8*)(V + (size_t)(b * SS + s0 + r) * KVDIM + kvh * HD + d0 + c8);
#pragma unroll
        for (int j = 0; j < 8; ++j) tile[r][c8 + j] = v[j];
    }
    __syncthreads();
#pragma unroll
    for (int i = 0; i < 2; ++i) {
        int o = i * 256 + t;
        int sseg = (o & 7) * 8, dl = o >> 3;
        bf16x8 v;
#pragma unroll
        for (int j = 0; j < 8; ++j) v[j] = tile[sseg + j][dl];
        *(bf16x8*)(Vt + ((size_t)((b * NKV + kvh) * HD) + d0 + dl) * SS + s0 + sseg) = v;
    }
}

// ---------------------------------------------------------------------------
// Flash attention, S^T formulation. (reverted to the measured-best R4 form:
// 4-wave / QBLK=128, 32KB LDS, P aliases Ks, counted-K-wait + deferred-V-wait,
// defer-max THR=8, tree reductions. R5 K-prefetch and R6 8-wave geometry both
// measured null/regression -- this structure's plateau is ~136us.)
// ---------------------------------------------------------------------------
__global__ __launch_bounds__(256, 2)
void flash_attn(const bf16* __restrict__ Q, const bf16* __restrict__ Kr,
                const bf16* __restrict__ Vt, bf16* __restrict__ AO) {
    __shared__ char smem[32768];
    bf16* Ks  = (bf16*)smem;               // [64 keys][128 d], 16B-slot swizzled
    bf16* Vts = (bf16*)(smem + 16384);     // [128 d][64 keys], swizzled
    char* Ps  = smem;                       // P [128 q][64 k], aliases Ks
    const int t = threadIdx.x, w = t >> 6, lane = t & 63;
    const int l15 = lane & 15, quad = lane >> 4;
    const int bh = blockIdx.x;
    const int b = bh >> 5, h = bh & 31, kvh = h >> 2;
    const int q0 = ((int)gridDim.y - 1 - (int)blockIdx.y) * 128;  // LPT

    bf16x8 qf[2][4];
#pragma unroll
    for (int mi = 0; mi < 2; ++mi) {
        int qrow = b * SS + q0 + w * 32 + mi * 16 + l15;
#pragma unroll
        for (int ks = 0; ks < 4; ++ks)
            qf[mi][ks] = *(const bf16x8*)(Q + (size_t)qrow * DIM + h * HD + ks * 32 + quad * 8);
    }

    f32x4 of[2][8] = {};
    float mrow[2] = {NEGINF, NEGINF};
    float lrow[2] = {0.f, 0.f};

    const int kend = q0 + 128;
    for (int kk = 0; kk < kend; kk += 64) {
        // stage K (4 loads) then V (4 loads); wait K only
#pragma unroll
        for (int i = 0; i < 4; ++i) {
            int s = i * 256 + t;
            int key = s >> 4, slot = s & 15;
            int dseg = slot ^ (key & 15);
            async16((char*)Ks + (size_t)s * 16,
                    Kr + (size_t)(b * SS + kk + key) * KVDIM + kvh * HD + dseg * 8);
        }
#pragma unroll
        for (int i = 0; i < 4; ++i) {
            int s = i * 256 + t;
            int d = s >> 3, slot = s & 7;
            int kseg = slot ^ (d & 7);
            async16((char*)Vts + (size_t)s * 16,
                    Vt + ((size_t)((b * NKV + kvh) * HD + d)) * SS + kk + kseg * 8);
        }
        VM4(); SBAR();                      // K landed (all waves); V in flight

        f32x4 sacc[2][4] = {};
#pragma unroll
        for (int nt = 0; nt < 4; ++nt) {
            int key = nt * 16 + l15;
#pragma unroll
            for (int ks = 0; ks < 4; ++ks) {
                int slot = (ks * 4 + quad) ^ (key & 15);
                bf16x8 kf = *(const bf16x8*)(Ks + key * 128 + slot * 8);
#pragma unroll
                for (int mi = 0; mi < 2; ++mi)
                    sacc[mi][nt] = mfma16(kf, qf[mi][ks], sacc[mi][nt]);
            }
        }
        if (kk >= q0) {
#pragma unroll
            for (int mi = 0; mi < 2; ++mi) {
                int q = q0 + w * 32 + mi * 16 + l15;
#pragma unroll
                for (int nt = 0; nt < 4; ++nt) {
                    int kbase = kk + nt * 16 + quad * 4;
#pragma unroll
                    for (int r = 0; r < 4; ++r)
                        if (kbase + r > q) sacc[mi][nt][r] = NEGINF;
                }
            }
        }
#pragma unroll
        for (int mi = 0; mi < 2; ++mi) {
            // tree max over 16 regs, then cross-lane
            float m01[4];
#pragma unroll
            for (int nt = 0; nt < 4; ++nt)
                m01[nt] = fmaxf(fmaxf(sacc[mi][nt][0], sacc[mi][nt][1]),
                                fmaxf(sacc[mi][nt][2], sacc[mi][nt][3]));
            float mx = fmaxf(fmaxf(m01[0], m01[1]), fmaxf(m01[2], m01[3]));
            mx = fmaxf(mx, __shfl_xor(mx, 16));
            mx = fmaxf(mx, __shfl_xor(mx, 32));
            if (__all(mx - mrow[mi] <= 8.0f)) {
                // defer: keep old max, no O-rescale
                float rs[4];
#pragma unroll
                for (int nt = 0; nt < 4; ++nt) {
                    rs[nt] = 0.f;
#pragma unroll
                    for (int r = 0; r < 4; ++r) {
                        float p = exp2f(sacc[mi][nt][r] - mrow[mi]);
                        sacc[mi][nt][r] = p;
                        rs[nt] += p;
                    }
                }
                float rsum = (rs[0] + rs[1]) + (rs[2] + rs[3]);
                rsum += __shfl_xor(rsum, 16);
                rsum += __shfl_xor(rsum, 32);
                lrow[mi] += rsum;
            } else {
                float mnew = fmaxf(mrow[mi], mx);
                float alpha = exp2f(mrow[mi] - mnew);
                float rs[4];
#pragma unroll
                for (int nt = 0; nt < 4; ++nt) {
                    rs[nt] = 0.f;
#pragma unroll
                    for (int r = 0; r < 4; ++r) {
                        float p = exp2f(sacc[mi][nt][r] - mnew);
                        sacc[mi][nt][r] = p;
                        rs[nt] += p;
                    }
                }
                float rsum = (rs[0] + rs[1]) + (rs[2] + rs[3]);
                rsum += __shfl_xor(rsum, 16);
                rsum += __shfl_xor(rsum, 32);
                lrow[mi] = lrow[mi] * alpha + rsum;
                mrow[mi] = mnew;
#pragma unroll
                for (int dt = 0; dt < 8; ++dt)
#pragma unroll
                    for (int r = 0; r < 4; ++r) of[mi][dt][r] *= alpha;
            }
        }
        VM0(); SBAR();                      // V landed; Ks reads done
#pragma unroll
        for (int mi = 0; mi < 2; ++mi) {
            int row = w * 32 + mi * 16 + l15;
#pragma unroll
            for (int nt = 0; nt < 4; ++nt) {
                bf16x4 pv;
#pragma unroll
                for (int r = 0; r < 4; ++r) pv[r] = (bf16)sacc[mi][nt][r];
                int cc = nt * 2 + (quad >> 1);
                *(bf16x4*)(Ps + row * 128 + ((cc ^ (row & 7)) * 16 + (quad & 1) * 8)) = pv;
            }
        }
#pragma unroll
        for (int kb = 0; kb < 2; ++kb) {
            bf16x8 pa[2];
#pragma unroll
            for (int mi = 0; mi < 2; ++mi) {
                int row = w * 32 + mi * 16 + l15;
                pa[mi] = *(const bf16x8*)(Ps + row * 128 + (((kb * 4 + quad) ^ (row & 7)) * 16));
            }
#pragma unroll
            for (int dt = 0; dt < 8; ++dt) {
                int d = dt * 16 + l15;
                int slot = (kb * 4 + quad) ^ (d & 7);
                bf16x8 vb = *(const bf16x8*)(Vts + d * 64 + slot * 8);
#pragma unroll
                for (int mi = 0; mi < 2; ++mi)
                    of[mi][dt] = mfma16(vb, pa[mi], of[mi][dt]);
            }
        }
        SBAR();                             // all Ps/Vts reads done -> restage
    }
    bf16* Os = (bf16*)smem;
#pragma unroll
    for (int mi = 0; mi < 2; ++mi) {
        float inv = 1.0f / lrow[mi];
        int row = w * 32 + mi * 16 + l15;
#pragma unroll
        for (int dt = 0; dt < 8; ++dt) {
            bf16x4 o4;
#pragma unroll
            for (int r = 0; r < 4; ++r) o4[r] = (bf16)(of[mi][dt][r] * inv);
            int s = dt * 2 + (quad >> 1);
            int slot = s ^ l15;
            *(bf16x4*)((char*)Os + row * 256 + slot * 16 + (quad & 1) * 8) = o4;
        }
    }
    __syncthreads();
#pragma unroll
    for (int i = 0; i < 8; ++i) {
        int flat = i * 256 + t;
        int ql = flat >> 4, s = flat & 15;
        bf16x8 v = *(const bf16x8*)((char*)Os + ql * 256 + (s ^ (ql & 15)) * 16);
        *(bf16x8*)(AO + (size_t)(b * SS + q0 + ql) * DIM + h * HD + s * 8) = v;
    }
}

// ---------------------------------------------------------------------------
extern "C" void kernel_launch(void* const* d_in, const int* in_sizes, int n_in,
                              void* d_out, int out_size, void* d_ws, size_t ws_size,
                              hipStream_t stream) {
    const size_t MD = (size_t)BB * SS * DIM;    // 16,777,216
    const size_t KV = (size_t)BB * SS * KVDIM;  //  4,194,304
    const size_t WQKV = (size_t)QKVN * DIM;     // 25,165,824
    const size_t FC = (size_t)SS * (HD / 2);
    const int M = BB * SS;

    int* flags = (int*)d_ws;
    bf16* xb  = (bf16*)((char*)d_ws + 32);  // x, later reused as attn output AO
    bf16* wb  = xb + MD;                    // weight staging (wq|wk|wv, later wo)
    bf16* Q   = wb + WQKV;
    bf16* Kr  = Q + MD;
    bf16* Vw  = Kr + KV;
    bf16* Vt  = Vw + KV;
    bf16* fcb = Vt + KV;
    bf16* fsb = fcb + FC;

    DetectArgs da;
    for (int i = 0; i < 7; ++i) { da.p[i] = d_in[i]; da.n[i] = in_sizes[i]; }
    detect_dtypes<<<7, 256, 0, stream>>>(da, flags);

    dim3 blk(256);
    dim3 blk512(512);

    // fused convert: x, wq, wk, wv, fc, fs  (everything before QKV gemm)
    {
        Conv6 c;
        c.s[0] = d_in[0]; c.d[0] = xb;            c.n[0] = (int)(MD / 8); c.f[0] = flags + 0;
        c.s[1] = d_in[1]; c.d[1] = wb;            c.n[1] = (int)(MD / 8); c.f[1] = flags + 1;
        c.s[2] = d_in[2]; c.d[2] = wb + MD;       c.n[2] = (int)(KV / 8); c.f[2] = flags + 2;
        c.s[3] = d_in[3]; c.d[3] = wb + MD + KV;  c.n[3] = (int)(KV / 8); c.f[3] = flags + 3;
        c.s[4] = d_in[5]; c.d[4] = fcb;           c.n[4] = (int)(FC / 8); c.f[4] = flags + 5;
        c.s[5] = d_in[6]; c.d[5] = fsb;           c.n[5] = (int)(FC / 8); c.f[5] = flags + 6;
        long total = 2L * (MD / 8) + 2L * (KV / 8) + 2L * (FC / 8);
        convert6<<<(int)((total + 255) / 256), blk, 0, stream>>>(c);
    }

    // fused Q+K+V projection (N = 6144, grid 24x16 = 384 blocks)
    gemm_qkv<<<dim3(QKVN / 256, M / 256), blk512, 0, stream>>>(xb, wb, Q, Kr, Vw, M, DIM);

    // fused RoPE(Q,K) + V transpose
    rope_tv<<<dim3(ROPE_BLOCKS + (SS / 64) * 16 * BB), blk, 0, stream>>>(Q, Kr, fcb, fsb, Vw, Vt);

    // flash attention -> AO (reuses xb)
    flash_attn<<<dim3(BB * NH, SS / 128), blk, 0, stream>>>(Q, Kr, Vt, xb);

    // output projection
    convert_to_bf16<<<(int)(MD / 8 / 256), blk, 0, stream>>>(d_in[4], wb, (int)(MD / 8), flags + 4);
    gemm_nt_out<<<dim3(DIM / 256, M / 256), blk512, 0, stream>>>(xb, wb, d_out, M, DIM, DIM, flags + 0);
}